// Round 1
// baseline (199.444 us; speedup 1.0000x reference)
//
#include <hip/hip_runtime.h>
#include <hip/hip_bf16.h>

#define B_ 32
#define T_ 512
#define F_ 9
#define H_ 64
#define P_ 84
#define LE_ 510
#define LBL_ 10

struct CombT { int c[P_][3]; };
__host__ __device__ constexpr CombT make_combs() {
    CombT t{}; int n = 0;
    for (int a = 0; a < F_; ++a)
        for (int b = a + 1; b < F_; ++b)
            for (int c = b + 1; c < F_; ++c) { t.c[n][0] = a; t.c[n][1] = b; t.c[n][2] = c; ++n; }
    return t;
}
__device__ __constant__ CombT COMB = make_combs();

// ---------------------------------------------------------------------------
// Kernel A: A[h][f*3+k] = sum_p va_w1[p] * sum_i [comb[p][i]==f] w[p,h,i,k]
//           Abias[h]    = va_b1[h] + sum_p va_w1[p]*conv_b[p,h]
// ---------------------------------------------------------------------------
__global__ __launch_bounds__(256) void precomp_kernel(
    const float* __restrict__ conv_w, const float* __restrict__ conv_b,
    const float* __restrict__ va_w1, const float* __restrict__ va_b1,
    float* __restrict__ A, float* __restrict__ Abias)
{
    __shared__ float sacc[256][28];
    int tid = threadIdx.x;
    int h = tid >> 2, q = tid & 3;            // 64 h  x  4 p-quarters
    for (int j = 0; j < 28; ++j) sacc[tid][j] = 0.f;
    for (int p = q * 21; p < (q + 1) * 21; ++p) {
        float w1 = va_w1[p];
        sacc[tid][27] += w1 * conv_b[p * H_ + h];
        const float* wp = conv_w + p * (H_ * 9) + h * 9;
        for (int i = 0; i < 3; ++i) {
            int f = COMB.c[p][i];
            for (int k = 0; k < 3; ++k) sacc[tid][f * 3 + k] += w1 * wp[i * 3 + k];
        }
    }
    __syncthreads();
    if (q == 0) {
        for (int j = 0; j < 27; ++j)
            A[h * 27 + j] = sacc[tid][j] + sacc[tid + 1][j] + sacc[tid + 2][j] + sacc[tid + 3][j];
        Abias[h] = va_b1[h] + sacc[tid][27] + sacc[tid + 1][27] + sacc[tid + 2][27] + sacc[tid + 3][27];
    }
}

// ---------------------------------------------------------------------------
// Kernel 1: per (b, 64-l tile): t1 -> t2 -> softmax -> attn-weighted conv
// recompute -> v[b][h][l].  lane = l, waves split H 8-ways.
// ---------------------------------------------------------------------------
__global__ __launch_bounds__(512) void va_kernel(
    const float* __restrict__ x,
    const float* __restrict__ conv_w, const float* __restrict__ conv_b,
    const float* __restrict__ va_w2, const float* __restrict__ va_b2,
    const float* __restrict__ A, const float* __restrict__ Abias,
    float* __restrict__ v)
{
    __shared__ float xs[66 * 9];        // rows l0 .. l0+65
    __shared__ float t1s[64][65];       // +1 pad: banks (ln+h)%32
    __shared__ float t2s[64][85];       // +1 pad: banks (21*ln+p)%32

    const int b = blockIdx.y;
    const int l0 = blockIdx.x * 64;
    const int tid = threadIdx.x;
    const int ln = tid & 63;
    const int wv = tid >> 6;            // wave 0..7

    // ---- stage x rows (contiguous copy, clamped at end of batch b) ----
    int maxidx = (T_ - l0) * F_; if (maxidx > 66 * F_) maxidx = 66 * F_;
    for (int i = tid; i < 66 * F_; i += 512)
        xs[i] = (i < maxidx) ? x[b * (T_ * F_) + l0 * F_ + i] : 0.f;
    __syncthreads();

    int valid = LE_ - l0; if (valid > 64) valid = 64;

    // ---- per-lane x window in registers (static indices only) ----
    float xw[27];
#pragma unroll
    for (int k = 0; k < 3; ++k)
#pragma unroll
        for (int f = 0; f < F_; ++f) xw[k * 9 + f] = xs[(ln + k) * F_ + f];

    // ---- pass A: t1[l=ln][h] for this wave's 8 h's via A-matrix ----
#pragma unroll
    for (int hh = 0; hh < 8; ++hh) {
        int h = wv * 8 + hh;
        const float* Ah = A + h * 27;
        float s = Abias[h];
#pragma unroll
        for (int f = 0; f < F_; ++f)
#pragma unroll
            for (int k = 0; k < 3; ++k) s = fmaf(xw[k * 9 + f], Ah[f * 3 + k], s);
        t1s[ln][h] = fmaxf(s, 0.f);
    }
    __syncthreads();

    // ---- t2[l=ln][p] for this wave's p-slice (h-major for reg accumulators) ----
    const int p0 = (wv < 4) ? wv * 11 : 44 + (wv - 4) * 10;
    const int p1 = (wv < 4) ? p0 + 11 : p0 + 10;
    {
        float t2acc[11];
#pragma unroll
        for (int j = 0; j < 11; ++j) t2acc[j] = (p0 + j < p1) ? va_b2[p0 + j] : 0.f;
        for (int h = 0; h < H_; ++h) {
            float tv = t1s[ln][h];
            const float* w2h = va_w2 + h * P_;
#pragma unroll
            for (int j = 0; j < 11; ++j)
                if (p0 + j < p1) t2acc[j] = fmaf(tv, w2h[p0 + j], t2acc[j]);
        }
#pragma unroll
        for (int j = 0; j < 11; ++j)
            if (p0 + j < p1) t2s[ln][p0 + j] = fmaxf(t2acc[j], 0.f);
    }
    __syncthreads();

    // ---- softmax params over own row (per lane) ----
    float mx = -1e30f;
    for (int p = 0; p < P_; ++p) mx = fmaxf(mx, t2s[ln][p]);
    float sum = 0.f;
    for (int p = 0; p < P_; ++p) sum += __expf(t2s[ln][p] - mx);
    float inv = 1.f / sum;

    // ---- pass B: attn-weighted conv recompute, this wave's 8 h's ----
    float acc[8];
#pragma unroll
    for (int i = 0; i < 8; ++i) acc[i] = 0.f;

    for (int p = 0; p < P_; ++p) {
        float ap = __expf(t2s[ln][p] - mx) * inv;
        // gather the 9 window values for this combo from LDS (lane-stride 9: conflict-free)
        float xv9[9];
#pragma unroll
        for (int i = 0; i < 3; ++i) {
            int f = COMB.c[p][i];
#pragma unroll
            for (int k = 0; k < 3; ++k) xv9[i * 3 + k] = xs[(ln + k) * F_ + f];
        }
        const float* wp = conv_w + p * (H_ * 9) + wv * 8 * 9;   // wave-uniform
        const float* bp = conv_b + p * H_ + wv * 8;
#pragma unroll
        for (int hh = 0; hh < 8; ++hh) {
            float cv = bp[hh];
#pragma unroll
            for (int j = 0; j < 9; ++j) cv = fmaf(xv9[j], wp[hh * 9 + j], cv);
            acc[hh] = fmaf(ap, cv, acc[hh]);
        }
    }

    if (ln < valid) {
#pragma unroll
        for (int hh = 0; hh < 8; ++hh) {
            int h = wv * 8 + hh;
            v[(b * H_ + h) * LE_ + l0 + ln] = acc[hh];
        }
    }
}

// ---------------------------------------------------------------------------
// Kernel 2: temporal attention + FC.  one block per b.
// ---------------------------------------------------------------------------
__global__ __launch_bounds__(256) void ta_kernel(
    const float* __restrict__ v,
    const float* __restrict__ ta_w1, const float* __restrict__ ta_b1,
    const float* __restrict__ ta_w2, const float* __restrict__ ta_b2,
    const float* __restrict__ fc_w, const float* __restrict__ fc_b,
    float* __restrict__ out)
{
    __shared__ float u1s[64];
    __shared__ float attns[512];
    __shared__ float red[256];
    __shared__ float zs[64];

    const int b = blockIdx.x;
    const int tid = threadIdx.x;
    const int h = tid >> 2, q = tid & 3;
    const int lbeg = q * 128;
    const int lend = (lbeg + 128 < LE_) ? lbeg + 128 : LE_;
    const float* vb = v + (b * H_ + h) * LE_;

    // u1 partials
    {
        float s = 0.f;
        for (int l = lbeg; l < lend; ++l) s = fmaf(vb[l], ta_w1[l], s);
        red[tid] = s;
    }
    __syncthreads();
    if (tid < 64)
        u1s[tid] = fmaxf(ta_b1[tid] + red[tid * 4] + red[tid * 4 + 1] + red[tid * 4 + 2] + red[tid * 4 + 3], 0.f);
    __syncthreads();

    // u2[l]
    for (int l = tid; l < LE_; l += 256) {
        float s = ta_b2[l];
        for (int hx = 0; hx < H_; ++hx) s = fmaf(u1s[hx], ta_w2[hx * LE_ + l], s);
        attns[l] = fmaxf(s, 0.f);
    }
    __syncthreads();

    // softmax over 510
    float m = -1e30f;
    for (int l = tid; l < LE_; l += 256) m = fmaxf(m, attns[l]);
    red[tid] = m; __syncthreads();
    for (int s = 128; s > 0; s >>= 1) { if (tid < s) red[tid] = fmaxf(red[tid], red[tid + s]); __syncthreads(); }
    m = red[0]; __syncthreads();

    float ssum = 0.f;
    for (int l = tid; l < LE_; l += 256) { float e = __expf(attns[l] - m); attns[l] = e; ssum += e; }
    red[tid] = ssum; __syncthreads();
    for (int s = 128; s > 0; s >>= 1) { if (tid < s) red[tid] += red[tid + s]; __syncthreads(); }
    float inv = 1.f / red[0]; __syncthreads();

    // z[h] partials (fold inv in)
    {
        float s = 0.f;
        for (int l = lbeg; l < lend; ++l) s = fmaf(vb[l], attns[l], s);
        red[tid] = s * inv;
    }
    __syncthreads();
    if (tid < 64)
        zs[tid] = red[tid * 4] + red[tid * 4 + 1] + red[tid * 4 + 2] + red[tid * 4 + 3];
    __syncthreads();

    if (tid < LBL_) {
        float s = fc_b[tid];
        for (int hx = 0; hx < H_; ++hx) s = fmaf(zs[hx], fc_w[tid * H_ + hx], s);
        out[b * LBL_ + tid] = s;
    }
}

extern "C" void kernel_launch(void* const* d_in, const int* in_sizes, int n_in,
                              void* d_out, int out_size, void* d_ws, size_t ws_size,
                              hipStream_t stream)
{
    const float* x      = (const float*)d_in[0];
    const float* conv_w = (const float*)d_in[1];
    const float* conv_b = (const float*)d_in[2];
    const float* va_w1  = (const float*)d_in[3];
    const float* va_b1  = (const float*)d_in[4];
    const float* va_w2  = (const float*)d_in[5];
    const float* va_b2  = (const float*)d_in[6];
    const float* ta_w1  = (const float*)d_in[7];
    const float* ta_b1  = (const float*)d_in[8];
    const float* ta_w2  = (const float*)d_in[9];
    const float* ta_b2  = (const float*)d_in[10];
    const float* fc_w   = (const float*)d_in[11];
    const float* fc_b   = (const float*)d_in[12];

    float* ws    = (float*)d_ws;
    float* A     = ws;            // 64*27 = 1728
    float* Abias = ws + 1728;     // 64
    float* v     = ws + 2048;     // 32*64*510 = 1,044,480

    precomp_kernel<<<1, 256, 0, stream>>>(conv_w, conv_b, va_w1, va_b1, A, Abias);
    va_kernel<<<dim3(8, B_), 512, 0, stream>>>(x, conv_w, conv_b, va_w2, va_b2, A, Abias, v);
    ta_kernel<<<B_, 256, 0, stream>>>(v, ta_w1, ta_b1, ta_w2, ta_b2, fc_w, fc_b, (float*)d_out);
}